// Round 1
// baseline (1299.421 us; speedup 1.0000x reference)
//
#include <hip/hip_runtime.h>

#define BB 8
#define CC 512
#define NT 4096
#define GG 8
#define CPG 64
#define EPSF 1e-6f
#define SQK 0.04419417382415922f  // 1/sqrt(512)

// ws offsets (floats)
#define OFF_AAFF 0
#define OFF_BAFF 4096
#define OFF_PB2  8192
#define OFF_KV   16384
#define OFF_CTX  (16384 + 8*1024*4096)
#define OFF_M    (OFF_CTX + 8*512*512)
#define OFF_P    OFF_CTX   // reuse: ctx dead after m_gemm

// ---------------- GroupNorm stats -> per-(b,c) affine ----------------
__global__ __launch_bounds__(256) void gn_stats(
    const float* __restrict__ x, const float* __restrict__ gn_scale,
    const float* __restrict__ gn_bias, float* __restrict__ a_aff,
    float* __restrict__ b_aff) {
  int bg = blockIdx.x;
  int b = bg / GG, g = bg % GG;
  const float4* p4 = (const float4*)(x + (size_t)(b * CC + g * CPG) * NT);
  int tid = threadIdx.x;
  float s = 0.f, sq = 0.f;
  for (int i = tid; i < (CPG * NT) / 4; i += 256) {
    float4 v = p4[i];
    s  += v.x + v.y + v.z + v.w;
    sq += v.x * v.x + v.y * v.y + v.z * v.z + v.w * v.w;
  }
  for (int off = 32; off > 0; off >>= 1) {
    s  += __shfl_down(s, off);
    sq += __shfl_down(sq, off);
  }
  __shared__ float ls[4], lq[4];
  __shared__ float sm, sr;
  int wid = tid >> 6, lane = tid & 63;
  if (lane == 0) { ls[wid] = s; lq[wid] = sq; }
  __syncthreads();
  if (tid == 0) {
    float ts = ls[0] + ls[1] + ls[2] + ls[3];
    float tq = lq[0] + lq[1] + lq[2] + lq[3];
    float mean = ts / (float)(CPG * NT);
    float var  = tq / (float)(CPG * NT) - mean * mean;
    sm = mean; sr = rsqrtf(var + EPSF);
  }
  __syncthreads();
  float mean = sm, rstd = sr;
  if (tid < CPG) {
    int c = g * CPG + tid;
    float a = gn_scale[c] * rstd;
    a_aff[b * CC + c] = a;
    b_aff[b * CC + c] = gn_bias[c] - mean * a;
  }
}

// ---------------- kv GEMM: kv[b,o,n] = sum_c W[512+o,c]*h[b,c,n] + bias ----
// h computed on the fly: h = a_aff[c]*x + b_aff[c]
__global__ __launch_bounds__(256) void kv_gemm(
    const float* __restrict__ x, const float* __restrict__ qkv_w,
    const float* __restrict__ qkv_b, const float* __restrict__ a_aff,
    const float* __restrict__ b_aff, float* __restrict__ kv) {
  __shared__ __align__(16) float As[16][68];  // [kk][m]
  __shared__ __align__(16) float Bs[16][68];  // [kk][n]
  int b = blockIdx.z;
  int n0 = blockIdx.x * 64;
  int m0 = blockIdx.y * 64;
  int tid = threadIdx.x;
  int tx = tid & 15, ty = tid >> 4;
  const float* A  = qkv_w + (size_t)CC * CC;  // skip q rows
  const float* xb = x + (size_t)b * CC * NT;
  const float* aa = a_aff + b * CC;
  const float* bb = b_aff + b * CC;
  float acc[4][4] = {};
  for (int k0 = 0; k0 < CC; k0 += 16) {
#pragma unroll
    for (int i = 0; i < 4; i++) {
      int idx = tid + i * 256;
      int m = idx >> 4, kk = idx & 15;
      As[kk][m] = A[(size_t)(m0 + m) * CC + k0 + kk];
    }
#pragma unroll
    for (int i = 0; i < 4; i++) {
      int idx = tid + i * 256;
      int kk = idx >> 6, tn = idx & 63;
      int c = k0 + kk;
      Bs[kk][tn] = aa[c] * xb[(size_t)c * NT + n0 + tn] + bb[c];
    }
    __syncthreads();
#pragma unroll
    for (int kk = 0; kk < 16; kk++) {
      float a[4], bv[4];
#pragma unroll
      for (int i = 0; i < 4; i++) a[i] = As[kk][ty * 4 + i];
#pragma unroll
      for (int j = 0; j < 4; j++) bv[j] = Bs[kk][tx * 4 + j];
#pragma unroll
      for (int i = 0; i < 4; i++)
#pragma unroll
        for (int j = 0; j < 4; j++) acc[i][j] += a[i] * bv[j];
    }
    __syncthreads();
  }
#pragma unroll
  for (int i = 0; i < 4; i++) {
    int o = m0 + ty * 4 + i;
    float bias = qkv_b[CC + o];
    float4 r;
    r.x = acc[i][0] + bias; r.y = acc[i][1] + bias;
    r.z = acc[i][2] + bias; r.w = acc[i][3] + bias;
    *(float4*)&kv[((size_t)b * 1024 + o) * NT + n0 + tx * 4] = r;
  }
}

// ---------------- softmax over tokens for k rows (in place) ---------------
__global__ __launch_bounds__(256) void softmax_k(float* __restrict__ kv) {
  int row = blockIdx.x;          // b*CC + d
  int b = row >> 9, d = row & 511;
  float* p = kv + ((size_t)b * 1024 + d) * NT;
  int tid = threadIdx.x;
  float v[16];
  float mx = -1e30f;
#pragma unroll
  for (int i = 0; i < 16; i++) { v[i] = p[tid + i * 256]; mx = fmaxf(mx, v[i]); }
  for (int off = 32; off > 0; off >>= 1) mx = fmaxf(mx, __shfl_down(mx, off));
  __shared__ float red[4];
  __shared__ float bmx, bs;
  int wid = tid >> 6, lane = tid & 63;
  if (lane == 0) red[wid] = mx;
  __syncthreads();
  if (tid == 0) bmx = fmaxf(fmaxf(red[0], red[1]), fmaxf(red[2], red[3]));
  __syncthreads();
  mx = bmx;
  float s = 0.f;
#pragma unroll
  for (int i = 0; i < 16; i++) { v[i] = expf(v[i] - mx); s += v[i]; }
  for (int off = 32; off > 0; off >>= 1) s += __shfl_down(s, off);
  __syncthreads();
  if (lane == 0) red[wid] = s;
  __syncthreads();
  if (tid == 0) bs = red[0] + red[1] + red[2] + red[3];
  __syncthreads();
  float inv = 1.f / bs;
#pragma unroll
  for (int i = 0; i < 16; i++) p[tid + i * 256] = v[i] * inv;
}

// ---------------- ctx GEMM (A*B^T): ctx[b,d,e] = sum_n k[d,n] v[e,n] ------
__global__ __launch_bounds__(256) void ctx_gemm(
    const float* __restrict__ kv, float* __restrict__ ctx) {
  __shared__ __align__(16) float As[16][68];  // [kk][d]
  __shared__ __align__(16) float Bs[16][68];  // [kk][e]
  int b = blockIdx.z;
  int e0 = blockIdx.x * 64, d0 = blockIdx.y * 64;
  int tid = threadIdx.x, tx = tid & 15, ty = tid >> 4;
  const float* K = kv + (size_t)b * 1024 * NT;
  const float* V = K + (size_t)512 * NT;
  float acc[4][4] = {};
  for (int k0 = 0; k0 < NT; k0 += 16) {
#pragma unroll
    for (int i = 0; i < 4; i++) {
      int idx = tid + i * 256;
      int m = idx >> 4, kk = idx & 15;
      As[kk][m] = K[(size_t)(d0 + m) * NT + k0 + kk];
      Bs[kk][m] = V[(size_t)(e0 + m) * NT + k0 + kk];
    }
    __syncthreads();
#pragma unroll
    for (int kk = 0; kk < 16; kk++) {
      float a[4], bv[4];
#pragma unroll
      for (int i = 0; i < 4; i++) a[i] = As[kk][ty * 4 + i];
#pragma unroll
      for (int j = 0; j < 4; j++) bv[j] = Bs[kk][tx * 4 + j];
#pragma unroll
      for (int i = 0; i < 4; i++)
#pragma unroll
        for (int j = 0; j < 4; j++) acc[i][j] += a[i] * bv[j];
    }
    __syncthreads();
  }
#pragma unroll
  for (int i = 0; i < 4; i++) {
    int d = d0 + ty * 4 + i;
    float4 r = {acc[i][0], acc[i][1], acc[i][2], acc[i][3]};
    *(float4*)&ctx[((size_t)b * CC + d) * CC + e0 + tx * 4] = r;
  }
}

// ---------------- M GEMM (A*B^T): M[b,o,d] = s*sum_e proj_w[o,e]*ctx[b,d,e]
__global__ __launch_bounds__(256) void m_gemm(
    const float* __restrict__ proj_w, const float* __restrict__ ctx,
    float* __restrict__ Mbuf) {
  __shared__ __align__(16) float As[16][68];
  __shared__ __align__(16) float Bs[16][68];
  int b = blockIdx.z;
  int d0 = blockIdx.x * 64, o0 = blockIdx.y * 64;
  int tid = threadIdx.x, tx = tid & 15, ty = tid >> 4;
  const float* Cb = ctx + (size_t)b * CC * CC;
  float acc[4][4] = {};
  for (int k0 = 0; k0 < CC; k0 += 16) {
#pragma unroll
    for (int i = 0; i < 4; i++) {
      int idx = tid + i * 256;
      int m = idx >> 4, kk = idx & 15;
      As[kk][m] = proj_w[(size_t)(o0 + m) * CC + k0 + kk];
      Bs[kk][m] = Cb[(size_t)(d0 + m) * CC + k0 + kk];
    }
    __syncthreads();
#pragma unroll
    for (int kk = 0; kk < 16; kk++) {
      float a[4], bv[4];
#pragma unroll
      for (int i = 0; i < 4; i++) a[i] = As[kk][ty * 4 + i];
#pragma unroll
      for (int j = 0; j < 4; j++) bv[j] = Bs[kk][tx * 4 + j];
#pragma unroll
      for (int i = 0; i < 4; i++)
#pragma unroll
        for (int j = 0; j < 4; j++) acc[i][j] += a[i] * bv[j];
    }
    __syncthreads();
  }
#pragma unroll
  for (int i = 0; i < 4; i++) {
    int o = o0 + ty * 4 + i;
    float4 r = {acc[i][0] * SQK, acc[i][1] * SQK, acc[i][2] * SQK, acc[i][3] * SQK};
    *(float4*)&Mbuf[((size_t)b * CC + o) * CC + d0 + tx * 4] = r;
  }
}

// ---------------- P GEMM (A*B): P[b,o,c] = sum_d M[b,o,d]*Wq[d,c] ---------
__global__ __launch_bounds__(256) void p_gemm(
    const float* __restrict__ Mbuf, const float* __restrict__ qkv_w,
    float* __restrict__ P) {
  __shared__ __align__(16) float As[16][68];
  __shared__ __align__(16) float Bs[16][68];
  int b = blockIdx.z;
  int c0 = blockIdx.x * 64, o0 = blockIdx.y * 64;
  int tid = threadIdx.x, tx = tid & 15, ty = tid >> 4;
  const float* A = Mbuf + (size_t)b * CC * CC;
  float acc[4][4] = {};
  for (int k0 = 0; k0 < CC; k0 += 16) {
#pragma unroll
    for (int i = 0; i < 4; i++) {
      int idx = tid + i * 256;
      int m = idx >> 4, kk = idx & 15;
      As[kk][m] = A[(size_t)(o0 + m) * CC + k0 + kk];
    }
#pragma unroll
    for (int i = 0; i < 4; i++) {
      int idx = tid + i * 256;
      int kk = idx >> 6, tn = idx & 63;
      Bs[kk][tn] = qkv_w[(size_t)(k0 + kk) * CC + c0 + tn];
    }
    __syncthreads();
#pragma unroll
    for (int kk = 0; kk < 16; kk++) {
      float a[4], bv[4];
#pragma unroll
      for (int i = 0; i < 4; i++) a[i] = As[kk][ty * 4 + i];
#pragma unroll
      for (int j = 0; j < 4; j++) bv[j] = Bs[kk][tx * 4 + j];
#pragma unroll
      for (int i = 0; i < 4; i++)
#pragma unroll
        for (int j = 0; j < 4; j++) acc[i][j] += a[i] * bv[j];
    }
    __syncthreads();
  }
#pragma unroll
  for (int i = 0; i < 4; i++) {
    int o = o0 + ty * 4 + i;
    float4 r = {acc[i][0], acc[i][1], acc[i][2], acc[i][3]};
    *(float4*)&P[((size_t)b * CC + o) * CC + c0 + tx * 4] = r;
  }
}

// ---------------- pb2[b,o] = sum_d M[b,o,d]*qkv_b[d] + proj_b[o] ----------
__global__ __launch_bounds__(512) void pb2_kernel(
    const float* __restrict__ Mbuf, const float* __restrict__ qkv_b,
    const float* __restrict__ proj_b, float* __restrict__ pb2) {
  int b = blockIdx.x, o = threadIdx.x;
  const float* Mr = Mbuf + ((size_t)b * CC + o) * CC;
  float s = 0.f;
  for (int d = 0; d < CC; d++) s += Mr[d] * qkv_b[d];
  pb2[b * CC + o] = s + proj_b[o];
}

// ---------------- final GEMM: out = x + P@h + pb2 -------------------------
__global__ __launch_bounds__(256) void final_gemm(
    const float* __restrict__ x, const float* __restrict__ P,
    const float* __restrict__ pb2, const float* __restrict__ a_aff,
    const float* __restrict__ b_aff, float* __restrict__ out) {
  __shared__ __align__(16) float As[16][68];
  __shared__ __align__(16) float Bs[16][68];
  int b = blockIdx.z;
  int n0 = blockIdx.x * 64;
  int o0 = blockIdx.y * 64;
  int tid = threadIdx.x, tx = tid & 15, ty = tid >> 4;
  const float* A  = P + (size_t)b * CC * CC;
  const float* xb = x + (size_t)b * CC * NT;
  const float* aa = a_aff + b * CC;
  const float* bb = b_aff + b * CC;
  float acc[4][4] = {};
  for (int k0 = 0; k0 < CC; k0 += 16) {
#pragma unroll
    for (int i = 0; i < 4; i++) {
      int idx = tid + i * 256;
      int m = idx >> 4, kk = idx & 15;
      As[kk][m] = A[(size_t)(o0 + m) * CC + k0 + kk];
    }
#pragma unroll
    for (int i = 0; i < 4; i++) {
      int idx = tid + i * 256;
      int kk = idx >> 6, tn = idx & 63;
      int c = k0 + kk;
      Bs[kk][tn] = aa[c] * xb[(size_t)c * NT + n0 + tn] + bb[c];
    }
    __syncthreads();
#pragma unroll
    for (int kk = 0; kk < 16; kk++) {
      float a[4], bv[4];
#pragma unroll
      for (int i = 0; i < 4; i++) a[i] = As[kk][ty * 4 + i];
#pragma unroll
      for (int j = 0; j < 4; j++) bv[j] = Bs[kk][tx * 4 + j];
#pragma unroll
      for (int i = 0; i < 4; i++)
#pragma unroll
        for (int j = 0; j < 4; j++) acc[i][j] += a[i] * bv[j];
    }
    __syncthreads();
  }
#pragma unroll
  for (int i = 0; i < 4; i++) {
    int o = o0 + ty * 4 + i;
    float bias = pb2[b * CC + o];
    const float4 xr = *(const float4*)&xb[(size_t)o * NT + n0 + tx * 4];
    float4 r;
    r.x = acc[i][0] + bias + xr.x;
    r.y = acc[i][1] + bias + xr.y;
    r.z = acc[i][2] + bias + xr.z;
    r.w = acc[i][3] + bias + xr.w;
    *(float4*)&out[((size_t)b * CC + o) * NT + n0 + tx * 4] = r;
  }
}

extern "C" void kernel_launch(void* const* d_in, const int* in_sizes, int n_in,
                              void* d_out, int out_size, void* d_ws, size_t ws_size,
                              hipStream_t stream) {
  const float* x        = (const float*)d_in[0];
  const float* qkv_w    = (const float*)d_in[1];
  const float* qkv_b    = (const float*)d_in[2];
  const float* proj_w   = (const float*)d_in[3];
  const float* proj_b   = (const float*)d_in[4];
  const float* gn_scale = (const float*)d_in[5];
  const float* gn_bias  = (const float*)d_in[6];
  float* out = (float*)d_out;
  float* ws  = (float*)d_ws;

  float* a_aff = ws + OFF_AAFF;
  float* b_aff = ws + OFF_BAFF;
  float* pb2   = ws + OFF_PB2;
  float* kv    = ws + OFF_KV;
  float* ctx   = ws + OFF_CTX;
  float* Mbuf  = ws + OFF_M;
  float* P     = ws + OFF_P;

  gn_stats<<<64, 256, 0, stream>>>(x, gn_scale, gn_bias, a_aff, b_aff);
  kv_gemm<<<dim3(64, 16, 8), 256, 0, stream>>>(x, qkv_w, qkv_b, a_aff, b_aff, kv);
  softmax_k<<<4096, 256, 0, stream>>>(kv);
  ctx_gemm<<<dim3(8, 8, 8), 256, 0, stream>>>(kv, ctx);
  m_gemm<<<dim3(8, 8, 8), 256, 0, stream>>>(proj_w, ctx, Mbuf);
  p_gemm<<<dim3(8, 8, 8), 256, 0, stream>>>(Mbuf, qkv_w, P);
  pb2_kernel<<<8, 512, 0, stream>>>(Mbuf, qkv_b, proj_b, pb2);
  final_gemm<<<dim3(64, 8, 8), 256, 0, stream>>>(x, P, pb2, a_aff, b_aff, out);
}

// Round 2
// 340.809 us; speedup vs baseline: 3.8128x; 3.8128x over previous
//
#include <hip/hip_runtime.h>

#define BB 8
#define CC 512
#define NT 4096
#define GG 8
#define CPG 64
#define EPSF 1e-6f
#define SQK 0.04419417382415922f  // 1/sqrt(512)

typedef __attribute__((ext_vector_type(8))) short bf16x8;
typedef __attribute__((ext_vector_type(4))) float f32x4;

// ws offsets (float units)
#define OFF_AAFF 0
#define OFF_BAFF 4096
#define OFF_PB2  8192
#define OFF_RED  12288
#define OFF_CTX  16384
#define OFF_M    (OFF_CTX + 2097152)
#define OFF_WKV  (OFF_M + 2097152)
#define OFF_PBF  (OFF_WKV + 262144)
#define OFF_HT   (OFF_PBF + 1048576)
#define OFF_KVB  (OFF_HT + 8388608)

__device__ __forceinline__ ushort f2bf(float f) {
  union { float f; uint u; } v; v.f = f;
  uint r = (v.u + 0x7fffu + ((v.u >> 16) & 1u)) >> 16;
  return (ushort)r;
}
__device__ __forceinline__ float bf2f(ushort h) {
  union { uint u; float f; } v; v.u = ((uint)h) << 16;
  return v.f;
}
__device__ __forceinline__ void gload16(const ushort* g, ushort* l) {
  __builtin_amdgcn_global_load_lds((const __attribute__((address_space(1))) void*)g,
                                   (__attribute__((address_space(3))) void*)l, 16, 0, 0);
}

// ---------------- GN stats: partial sums (512 blocks) ----------------
__global__ __launch_bounds__(256) void gn_stats1(const float* __restrict__ x,
                                                 float* __restrict__ red) {
  int bg = blockIdx.y, chunk = blockIdx.x;
  const float4* p4 = (const float4*)(x + (size_t)bg * (CPG * NT) + (size_t)chunk * 32768);
  int tid = threadIdx.x;
  float s = 0.f, sq = 0.f;
  for (int i = tid; i < 8192; i += 256) {
    float4 v = p4[i];
    s  += v.x + v.y + v.z + v.w;
    sq += v.x * v.x + v.y * v.y + v.z * v.z + v.w * v.w;
  }
  for (int off = 32; off > 0; off >>= 1) {
    s  += __shfl_down(s, off);
    sq += __shfl_down(sq, off);
  }
  __shared__ float ls[4], lq[4];
  int wid = tid >> 6, lane = tid & 63;
  if (lane == 0) { ls[wid] = s; lq[wid] = sq; }
  __syncthreads();
  if (tid == 0) {
    red[(bg * 8 + chunk) * 2]     = ls[0] + ls[1] + ls[2] + ls[3];
    red[(bg * 8 + chunk) * 2 + 1] = lq[0] + lq[1] + lq[2] + lq[3];
  }
}

// ---------------- GN stats reduce -> per-(b,c) affine ----------------
__global__ __launch_bounds__(64) void gn_stats2(
    const float* __restrict__ red, const float* __restrict__ gn_scale,
    const float* __restrict__ gn_bias, float* __restrict__ a_aff,
    float* __restrict__ b_aff) {
  int bg = blockIdx.x, b = bg >> 3, g = bg & 7;
  float s = 0.f, sq = 0.f;
  for (int i = 0; i < 8; i++) {
    s  += red[(bg * 8 + i) * 2];
    sq += red[(bg * 8 + i) * 2 + 1];
  }
  float mean = s / (float)(CPG * NT);
  float var  = sq / (float)(CPG * NT) - mean * mean;
  float rstd = rsqrtf(var + EPSF);
  int c = g * CPG + threadIdx.x;
  float a = gn_scale[c] * rstd;
  a_aff[b * CC + c] = a;
  b_aff[b * CC + c] = gn_bias[c] - mean * a;
}

// ---------------- convert kv weight rows to bf16 ----------------
__global__ __launch_bounds__(256) void wconv(const float* __restrict__ qkv_w,
                                             ushort* __restrict__ wkvb) {
  int idx = (blockIdx.x * 256 + threadIdx.x) * 4;
  float4 v = *(const float4*)(qkv_w + (size_t)CC * CC + idx);
  uint w0 = (uint)f2bf(v.x) | ((uint)f2bf(v.y) << 16);
  uint w1 = (uint)f2bf(v.z) | ((uint)f2bf(v.w) << 16);
  *(uint2*)(wkvb + idx) = make_uint2(w0, w1);
}

// ---------------- h^T in bf16: hT[b,n,c] = a[c]*x[b,c,n]+b[c] ----------------
__global__ __launch_bounds__(256) void ht_kernel(
    const float* __restrict__ x, const float* __restrict__ a_aff,
    const float* __restrict__ b_aff, ushort* __restrict__ hT) {
  __shared__ float ts[64][68];
  int b = blockIdx.z, c0 = blockIdx.y * 64, n0 = blockIdx.x * 64;
  int tid = threadIdx.x;
  int tn = (tid & 15) * 4, tc = tid >> 4;
#pragma unroll
  for (int it = 0; it < 4; it++) {
    int c = tc + it * 16;
    float a  = a_aff[b * CC + c0 + c];
    float bb = b_aff[b * CC + c0 + c];
    float4 v = *(const float4*)(x + ((size_t)(b * CC + c0 + c)) * NT + n0 + tn);
    ts[c][tn]     = a * v.x + bb;
    ts[c][tn + 1] = a * v.y + bb;
    ts[c][tn + 2] = a * v.z + bb;
    ts[c][tn + 3] = a * v.w + bb;
  }
  __syncthreads();
#pragma unroll
  for (int it = 0; it < 2; it++) {
    int idx = tid + it * 256;
    int n = idx >> 3, c8 = (idx & 7) * 8;
    uint w[4];
#pragma unroll
    for (int j = 0; j < 4; j++) {
      ushort lo = f2bf(ts[c8 + 2 * j][n]);
      ushort hi = f2bf(ts[c8 + 2 * j + 1][n]);
      w[j] = (uint)lo | ((uint)hi << 16);
    }
    uint4 ww = make_uint4(w[0], w[1], w[2], w[3]);
    *(uint4*)&hT[((size_t)b * NT + n0 + n) * CC + c0 + c8] = ww;
  }
}

// ---------------- shared MFMA mainloop: C[128][128] = A[128][K] * B[128][K]^T
template <int KTOT, int LDA, int LDB>
__device__ __forceinline__ void mfma_loop(const ushort* __restrict__ A,
                                          const ushort* __restrict__ B,
                                          ushort* As, ushort* Bs, int tid,
                                          f32x4 acc[4][4]) {
  int wave = tid >> 6, lane = tid & 63;
  int kofs = (lane & 3) * 8;
  int r0 = wave * 16 + (lane >> 2);
  int r1 = (wave + 4) * 16 + (lane >> 2);
  const ushort* ga0 = A + (size_t)r0 * LDA + kofs;
  const ushort* ga1 = A + (size_t)r1 * LDA + kofs;
  const ushort* gb0 = B + (size_t)r0 * LDB + kofs;
  const ushort* gb1 = B + (size_t)r1 * LDB + kofs;
  ushort* la0 = As + wave * 512;
  ushort* la1 = As + (wave + 4) * 512;
  ushort* lb0 = Bs + wave * 512;
  ushort* lb1 = Bs + (wave + 4) * 512;
  int wm = (wave >> 1) * 64, wn = (wave & 1) * 64;
  int aoff = (wm + (lane & 15)) * 32 + (lane >> 4) * 8;
  int boff = (wn + (lane & 15)) * 32 + (lane >> 4) * 8;
#pragma unroll 1
  for (int k0 = 0; k0 < KTOT; k0 += 32) {
    gload16(ga0, la0); gload16(ga1, la1);
    gload16(gb0, lb0); gload16(gb1, lb1);
    ga0 += 32; ga1 += 32; gb0 += 32; gb1 += 32;
    __syncthreads();   // drains vmcnt before barrier -> staged data visible
    bf16x8 a[4], b[4];
#pragma unroll
    for (int m = 0; m < 4; m++) a[m] = *(const bf16x8*)(As + aoff + m * 512);
#pragma unroll
    for (int n = 0; n < 4; n++) b[n] = *(const bf16x8*)(Bs + boff + n * 512);
#pragma unroll
    for (int m = 0; m < 4; m++)
#pragma unroll
      for (int n = 0; n < 4; n++)
        acc[m][n] = __builtin_amdgcn_mfma_f32_16x16x32_bf16(a[m], b[n], acc[m][n], 0, 0, 0);
    __syncthreads();
  }
}

// ---------------- kv GEMM bf16: kvb[b,o,n] = sum_c Wkv[o,c] hT[n,c] + bias ---
__global__ __launch_bounds__(256) void kv_gemm_bf16(
    const ushort* __restrict__ wkvb, const ushort* __restrict__ hT,
    const float* __restrict__ qkv_b, ushort* __restrict__ kvb) {
  __shared__ ushort As[4096], Bs[4096];
  int b = blockIdx.z, n0 = blockIdx.x * 128, m0 = blockIdx.y * 128;
  int tid = threadIdx.x;
  f32x4 acc[4][4] = {{{0.f, 0.f, 0.f, 0.f}}};
  const ushort* A = wkvb + (size_t)m0 * CC;
  const ushort* B = hT + (size_t)b * NT * CC + (size_t)n0 * CC;
  mfma_loop<CC, CC, CC>(A, B, As, Bs, tid, acc);
  int wave = tid >> 6, lane = tid & 63;
  int wm = (wave >> 1) * 64, wn = (wave & 1) * 64;
  int col = lane & 15, rb = (lane >> 4) * 4;
#pragma unroll
  for (int m = 0; m < 4; m++)
#pragma unroll
    for (int n = 0; n < 4; n++)
#pragma unroll
      for (int j = 0; j < 4; j++) {
        int gm = m0 + wm + m * 16 + rb + j;
        int gn = n0 + wn + n * 16 + col;
        float val = acc[m][n][j] + qkv_b[CC + gm];
        kvb[((size_t)(b * 1024 + gm)) * NT + gn] = f2bf(val);
      }
}

// ---------------- softmax over tokens (bf16 in place, k rows only) ----------
__global__ __launch_bounds__(256) void softmax_bf16(ushort* __restrict__ kvb) {
  int row = blockIdx.x;  // b*512 + d
  int b = row >> 9, d = row & 511;
  ushort* p = kvb + ((size_t)(b * 1024 + d)) * NT;
  int tid = threadIdx.x;
  uint4 r0 = *(const uint4*)(p + tid * 16);
  uint4 r1 = *(const uint4*)(p + tid * 16 + 8);
  float v[16];
  uint ws_[8] = {r0.x, r0.y, r0.z, r0.w, r1.x, r1.y, r1.z, r1.w};
#pragma unroll
  for (int i = 0; i < 8; i++) {
    union { uint u; float f; } lo, hi;
    lo.u = ws_[i] << 16; hi.u = ws_[i] & 0xffff0000u;
    v[2 * i] = lo.f; v[2 * i + 1] = hi.f;
  }
  float mx = -1e30f;
#pragma unroll
  for (int i = 0; i < 16; i++) mx = fmaxf(mx, v[i]);
  for (int off = 32; off > 0; off >>= 1) mx = fmaxf(mx, __shfl_down(mx, off));
  __shared__ float red[4];
  __shared__ float bmx, bs;
  int wid = tid >> 6, lane = tid & 63;
  if (lane == 0) red[wid] = mx;
  __syncthreads();
  if (tid == 0) bmx = fmaxf(fmaxf(red[0], red[1]), fmaxf(red[2], red[3]));
  __syncthreads();
  mx = bmx;
  float s = 0.f;
#pragma unroll
  for (int i = 0; i < 16; i++) { v[i] = expf(v[i] - mx); s += v[i]; }
  for (int off = 32; off > 0; off >>= 1) s += __shfl_down(s, off);
  __syncthreads();
  if (lane == 0) red[wid] = s;
  __syncthreads();
  if (tid == 0) bs = red[0] + red[1] + red[2] + red[3];
  __syncthreads();
  float inv = 1.f / bs;
  uint out[8];
#pragma unroll
  for (int i = 0; i < 8; i++) {
    ushort lo = f2bf(v[2 * i] * inv);
    ushort hi = f2bf(v[2 * i + 1] * inv);
    out[i] = (uint)lo | ((uint)hi << 16);
  }
  *(uint4*)(p + tid * 16)     = make_uint4(out[0], out[1], out[2], out[3]);
  *(uint4*)(p + tid * 16 + 8) = make_uint4(out[4], out[5], out[6], out[7]);
}

// ---------------- ctx GEMM bf16: ctx[b,d,e] = sum_n k[d,n] v[e,n] -----------
__global__ __launch_bounds__(256) void ctx_gemm_bf16(
    const ushort* __restrict__ kvb, float* __restrict__ ctx) {
  __shared__ ushort As[4096], Bs[4096];
  int b = blockIdx.z, e0 = blockIdx.x * 128, d0 = blockIdx.y * 128;
  int tid = threadIdx.x;
  f32x4 acc[4][4] = {{{0.f, 0.f, 0.f, 0.f}}};
  const ushort* K = kvb + (size_t)b * 1024 * NT + (size_t)d0 * NT;
  const ushort* V = kvb + ((size_t)b * 1024 + 512) * NT + (size_t)e0 * NT;
  mfma_loop<NT, NT, NT>(K, V, As, Bs, tid, acc);
  int wave = tid >> 6, lane = tid & 63;
  int wm = (wave >> 1) * 64, wn = (wave & 1) * 64;
  int col = lane & 15, rb = (lane >> 4) * 4;
#pragma unroll
  for (int m = 0; m < 4; m++)
#pragma unroll
    for (int n = 0; n < 4; n++)
#pragma unroll
      for (int j = 0; j < 4; j++) {
        int gd = d0 + wm + m * 16 + rb + j;
        int ge = e0 + wn + n * 16 + col;
        ctx[((size_t)b * CC + gd) * CC + ge] = acc[m][n][j];
      }
}

// ---------------- M GEMM f32 (A*B^T): M[b,o,d] = s*sum_e proj_w[o,e]*ctx[b,d,e]
__global__ __launch_bounds__(256) void m_gemm(
    const float* __restrict__ proj_w, const float* __restrict__ ctx,
    float* __restrict__ Mbuf) {
  __shared__ __align__(16) float As[16][68];
  __shared__ __align__(16) float Bs[16][68];
  int b = blockIdx.z;
  int d0 = blockIdx.x * 64, o0 = blockIdx.y * 64;
  int tid = threadIdx.x, tx = tid & 15, ty = tid >> 4;
  const float* Cb = ctx + (size_t)b * CC * CC;
  float acc[4][4] = {};
  for (int k0 = 0; k0 < CC; k0 += 16) {
#pragma unroll
    for (int i = 0; i < 4; i++) {
      int idx = tid + i * 256;
      int m = idx >> 4, kk = idx & 15;
      As[kk][m] = proj_w[(size_t)(o0 + m) * CC + k0 + kk];
      Bs[kk][m] = Cb[(size_t)(d0 + m) * CC + k0 + kk];
    }
    __syncthreads();
#pragma unroll
    for (int kk = 0; kk < 16; kk++) {
      float a[4], bv[4];
#pragma unroll
      for (int i = 0; i < 4; i++) a[i] = As[kk][ty * 4 + i];
#pragma unroll
      for (int j = 0; j < 4; j++) bv[j] = Bs[kk][tx * 4 + j];
#pragma unroll
      for (int i = 0; i < 4; i++)
#pragma unroll
        for (int j = 0; j < 4; j++) acc[i][j] += a[i] * bv[j];
    }
    __syncthreads();
  }
#pragma unroll
  for (int i = 0; i < 4; i++) {
    int o = o0 + ty * 4 + i;
    float4 r = {acc[i][0] * SQK, acc[i][1] * SQK, acc[i][2] * SQK, acc[i][3] * SQK};
    *(float4*)&Mbuf[((size_t)b * CC + o) * CC + d0 + tx * 4] = r;
  }
}

// ---------------- P GEMM f32 (A*B): P[b,o,c] = sum_d M[b,o,d]*Wq[d,c] -> bf16
__global__ __launch_bounds__(256) void p_gemm(
    const float* __restrict__ Mbuf, const float* __restrict__ qkv_w,
    ushort* __restrict__ Pb) {
  __shared__ __align__(16) float As[16][68];
  __shared__ __align__(16) float Bs[16][68];
  int b = blockIdx.z;
  int c0 = blockIdx.x * 64, o0 = blockIdx.y * 64;
  int tid = threadIdx.x, tx = tid & 15, ty = tid >> 4;
  const float* A = Mbuf + (size_t)b * CC * CC;
  float acc[4][4] = {};
  for (int k0 = 0; k0 < CC; k0 += 16) {
#pragma unroll
    for (int i = 0; i < 4; i++) {
      int idx = tid + i * 256;
      int m = idx >> 4, kk = idx & 15;
      As[kk][m] = A[(size_t)(o0 + m) * CC + k0 + kk];
    }
#pragma unroll
    for (int i = 0; i < 4; i++) {
      int idx = tid + i * 256;
      int kk = idx >> 6, tn = idx & 63;
      Bs[kk][tn] = qkv_w[(size_t)(k0 + kk) * CC + c0 + tn];
    }
    __syncthreads();
#pragma unroll
    for (int kk = 0; kk < 16; kk++) {
      float a[4], bv[4];
#pragma unroll
      for (int i = 0; i < 4; i++) a[i] = As[kk][ty * 4 + i];
#pragma unroll
      for (int j = 0; j < 4; j++) bv[j] = Bs[kk][tx * 4 + j];
#pragma unroll
      for (int i = 0; i < 4; i++)
#pragma unroll
        for (int j = 0; j < 4; j++) acc[i][j] += a[i] * bv[j];
    }
    __syncthreads();
  }
#pragma unroll
  for (int i = 0; i < 4; i++) {
    int o = o0 + ty * 4 + i;
    uint w0 = (uint)f2bf(acc[i][0]) | ((uint)f2bf(acc[i][1]) << 16);
    uint w1 = (uint)f2bf(acc[i][2]) | ((uint)f2bf(acc[i][3]) << 16);
    *(uint2*)&Pb[((size_t)b * CC + o) * CC + c0 + tx * 4] = make_uint2(w0, w1);
  }
}

// ---------------- pb2[b,o] = sum_d M[b,o,d]*qkv_b[d] + proj_b[o] ----------
__global__ __launch_bounds__(512) void pb2_kernel(
    const float* __restrict__ Mbuf, const float* __restrict__ qkv_b,
    const float* __restrict__ proj_b, float* __restrict__ pb2) {
  int b = blockIdx.x, o = threadIdx.x;
  const float* Mr = Mbuf + ((size_t)b * CC + o) * CC;
  float s = 0.f;
  for (int d = 0; d < CC; d++) s += Mr[d] * qkv_b[d];
  pb2[b * CC + o] = s + proj_b[o];
}

// ---------------- final GEMM bf16: out = x + P@h + pb2 ----------------------
__global__ __launch_bounds__(256) void final_gemm_bf16(
    const float* __restrict__ x, const ushort* __restrict__ Pb,
    const ushort* __restrict__ hT, const float* __restrict__ pb2,
    float* __restrict__ out) {
  __shared__ ushort As[4096], Bs[4096];
  int b = blockIdx.z, n0 = blockIdx.x * 128, m0 = blockIdx.y * 128;
  int tid = threadIdx.x;
  f32x4 acc[4][4] = {{{0.f, 0.f, 0.f, 0.f}}};
  const ushort* A = Pb + (size_t)b * CC * CC + (size_t)m0 * CC;
  const ushort* B = hT + (size_t)b * NT * CC + (size_t)n0 * CC;
  mfma_loop<CC, CC, CC>(A, B, As, Bs, tid, acc);
  int wave = tid >> 6, lane = tid & 63;
  int wm = (wave >> 1) * 64, wn = (wave & 1) * 64;
  int col = lane & 15, rb = (lane >> 4) * 4;
#pragma unroll
  for (int m = 0; m < 4; m++)
#pragma unroll
    for (int n = 0; n < 4; n++)
#pragma unroll
      for (int j = 0; j < 4; j++) {
        int gm = m0 + wm + m * 16 + rb + j;
        int gn = n0 + wn + n * 16 + col;
        size_t idx = ((size_t)(b * CC + gm)) * NT + gn;
        out[idx] = acc[m][n][j] + pb2[b * CC + gm] + x[idx];
      }
}

extern "C" void kernel_launch(void* const* d_in, const int* in_sizes, int n_in,
                              void* d_out, int out_size, void* d_ws, size_t ws_size,
                              hipStream_t stream) {
  const float* x        = (const float*)d_in[0];
  const float* qkv_w    = (const float*)d_in[1];
  const float* qkv_b    = (const float*)d_in[2];
  const float* proj_w   = (const float*)d_in[3];
  const float* proj_b   = (const float*)d_in[4];
  const float* gn_scale = (const float*)d_in[5];
  const float* gn_bias  = (const float*)d_in[6];
  float* out = (float*)d_out;
  float* ws  = (float*)d_ws;

  float*  a_aff = ws + OFF_AAFF;
  float*  b_aff = ws + OFF_BAFF;
  float*  pb2   = ws + OFF_PB2;
  float*  red   = ws + OFF_RED;
  float*  ctx   = ws + OFF_CTX;
  float*  Mbuf  = ws + OFF_M;
  ushort* wkvb  = (ushort*)(ws + OFF_WKV);
  ushort* Pb    = (ushort*)(ws + OFF_PBF);
  ushort* hT    = (ushort*)(ws + OFF_HT);
  ushort* kvb   = (ushort*)(ws + OFF_KVB);

  gn_stats1<<<dim3(8, 64), 256, 0, stream>>>(x, red);
  gn_stats2<<<64, 64, 0, stream>>>(red, gn_scale, gn_bias, a_aff, b_aff);
  wconv<<<512, 256, 0, stream>>>(qkv_w, wkvb);
  ht_kernel<<<dim3(64, 8, 8), 256, 0, stream>>>(x, a_aff, b_aff, hT);
  kv_gemm_bf16<<<dim3(32, 8, 8), 256, 0, stream>>>(wkvb, hT, qkv_b, kvb);
  softmax_bf16<<<4096, 256, 0, stream>>>(kvb);
  ctx_gemm_bf16<<<dim3(4, 4, 8), 256, 0, stream>>>(kvb, ctx);
  m_gemm<<<dim3(8, 8, 8), 256, 0, stream>>>(proj_w, ctx, Mbuf);
  p_gemm<<<dim3(8, 8, 8), 256, 0, stream>>>(Mbuf, qkv_w, Pb);
  pb2_kernel<<<8, 512, 0, stream>>>(Mbuf, qkv_b, proj_b, pb2);
  final_gemm_bf16<<<dim3(32, 4, 8), 256, 0, stream>>>(x, Pb, hT, pb2, out);
}

// Round 3
// 242.087 us; speedup vs baseline: 5.3676x; 1.4078x over previous
//
#include <hip/hip_runtime.h>

#define BB 8
#define CC 512
#define NT 4096
#define GG 8
#define CPG 64
#define EPSF 1e-6f
#define SQK 0.04419417382415922f  // 1/sqrt(512)

typedef __attribute__((ext_vector_type(8))) short bf16x8;
typedef __attribute__((ext_vector_type(4))) float f32x4;

// ws offsets (float units)
#define OFF_AAFF 0
#define OFF_BAFF 4096
#define OFF_PB2  8192
#define OFF_RED  12288
#define OFF_PCTX 16384                    // bf16 partial ctx: 8 splits x 8b x 512x512
#define OFF_CTXB (OFF_PCTX + 8388608)     // bf16 ctx
#define OFF_WKV  (OFF_CTXB + 1048576)     // bf16 kv weights [1024][512]
#define OFF_PW   (OFF_WKV + 262144)       // bf16 proj_w [512][512]
#define OFF_WQT  (OFF_PW + 131072)        // bf16 Wq^T [c][d]
#define OFF_MB   (OFF_WQT + 131072)       // bf16 M [b][o][d]
#define OFF_PBF  (OFF_MB + 1048576)       // bf16 P [b][o][c]
#define OFF_HT   (OFF_PBF + 1048576)      // bf16 h^T [b][n][c]
#define OFF_KVB  (OFF_HT + 8388608)       // bf16 kv [b][1024][n]

__device__ __forceinline__ ushort f2bf(float f) {
  union { float f; uint u; } v; v.f = f;
  uint r = (v.u + 0x7fffu + ((v.u >> 16) & 1u)) >> 16;
  return (ushort)r;
}
__device__ __forceinline__ float bf2f(ushort h) {
  union { uint u; float f; } v; v.u = ((uint)h) << 16;
  return v.f;
}
__device__ __forceinline__ void gload16(const ushort* g, ushort* l) {
  __builtin_amdgcn_global_load_lds((const __attribute__((address_space(1))) void*)g,
                                   (__attribute__((address_space(3))) void*)l, 16, 0, 0);
}

// ---------------- GN stats: partial sums ----------------
__global__ __launch_bounds__(256) void gn_stats1(const float* __restrict__ x,
                                                 float* __restrict__ red) {
  int bg = blockIdx.y, chunk = blockIdx.x;
  const float4* p4 = (const float4*)(x + (size_t)bg * (CPG * NT) + (size_t)chunk * 32768);
  int tid = threadIdx.x;
  float s = 0.f, sq = 0.f;
  for (int i = tid; i < 8192; i += 256) {
    float4 v = p4[i];
    s  += v.x + v.y + v.z + v.w;
    sq += v.x * v.x + v.y * v.y + v.z * v.z + v.w * v.w;
  }
  for (int off = 32; off > 0; off >>= 1) {
    s  += __shfl_down(s, off);
    sq += __shfl_down(sq, off);
  }
  __shared__ float ls[4], lq[4];
  int wid = tid >> 6, lane = tid & 63;
  if (lane == 0) { ls[wid] = s; lq[wid] = sq; }
  __syncthreads();
  if (tid == 0) {
    red[(bg * 8 + chunk) * 2]     = ls[0] + ls[1] + ls[2] + ls[3];
    red[(bg * 8 + chunk) * 2 + 1] = lq[0] + lq[1] + lq[2] + lq[3];
  }
}

__global__ __launch_bounds__(64) void gn_stats2(
    const float* __restrict__ red, const float* __restrict__ gn_scale,
    const float* __restrict__ gn_bias, float* __restrict__ a_aff,
    float* __restrict__ b_aff) {
  int bg = blockIdx.x, b = bg >> 3, g = bg & 7;
  float s = 0.f, sq = 0.f;
  for (int i = 0; i < 8; i++) {
    s  += red[(bg * 8 + i) * 2];
    sq += red[(bg * 8 + i) * 2 + 1];
  }
  float mean = s / (float)(CPG * NT);
  float var  = sq / (float)(CPG * NT) - mean * mean;
  float rstd = rsqrtf(var + EPSF);
  int c = g * CPG + threadIdx.x;
  float a = gn_scale[c] * rstd;
  a_aff[b * CC + c] = a;
  b_aff[b * CC + c] = gn_bias[c] - mean * a;
}

// ---------------- weight converts ----------------
__global__ __launch_bounds__(256) void wconv_kv(const float* __restrict__ qkv_w,
                                                ushort* __restrict__ wkvb) {
  int idx = (blockIdx.x * 256 + threadIdx.x) * 4;
  float4 v = *(const float4*)(qkv_w + (size_t)CC * CC + idx);
  uint w0 = (uint)f2bf(v.x) | ((uint)f2bf(v.y) << 16);
  uint w1 = (uint)f2bf(v.z) | ((uint)f2bf(v.w) << 16);
  *(uint2*)(wkvb + idx) = make_uint2(w0, w1);
}

__global__ __launch_bounds__(256) void wconv_pw(const float* __restrict__ proj_w,
                                                ushort* __restrict__ pwb) {
  int idx = (blockIdx.x * 256 + threadIdx.x) * 4;
  float4 v = *(const float4*)(proj_w + idx);
  uint w0 = (uint)f2bf(v.x) | ((uint)f2bf(v.y) << 16);
  uint w1 = (uint)f2bf(v.z) | ((uint)f2bf(v.w) << 16);
  *(uint2*)(pwb + idx) = make_uint2(w0, w1);
}

// Wq^T bf16: wqT[c][d] = qkv_w[d][c]  (q rows)
__global__ __launch_bounds__(256) void wqt_kernel(const float* __restrict__ qkv_w,
                                                  ushort* __restrict__ wqT) {
  __shared__ float t[32][33];
  int d0 = blockIdx.y * 32, c0 = blockIdx.x * 32;
  int tid = threadIdx.x;
  int r = tid >> 3, c4 = (tid & 7) * 4;
  float4 v = *(const float4*)(qkv_w + (size_t)(d0 + r) * CC + c0 + c4);
  t[r][c4] = v.x; t[r][c4 + 1] = v.y; t[r][c4 + 2] = v.z; t[r][c4 + 3] = v.w;
  __syncthreads();
  int r2 = tid >> 3, d4 = (tid & 7) * 4;
  uint w0 = (uint)f2bf(t[d4][r2])     | ((uint)f2bf(t[d4 + 1][r2]) << 16);
  uint w1 = (uint)f2bf(t[d4 + 2][r2]) | ((uint)f2bf(t[d4 + 3][r2]) << 16);
  *(uint2*)&wqT[(size_t)(c0 + r2) * CC + d0 + d4] = make_uint2(w0, w1);
}

// ---------------- h^T in bf16 ----------------
__global__ __launch_bounds__(256) void ht_kernel(
    const float* __restrict__ x, const float* __restrict__ a_aff,
    const float* __restrict__ b_aff, ushort* __restrict__ hT) {
  __shared__ float ts[64][68];
  int b = blockIdx.z, c0 = blockIdx.y * 64, n0 = blockIdx.x * 64;
  int tid = threadIdx.x;
  int tn = (tid & 15) * 4, tc = tid >> 4;
#pragma unroll
  for (int it = 0; it < 4; it++) {
    int c = tc + it * 16;
    float a  = a_aff[b * CC + c0 + c];
    float bb = b_aff[b * CC + c0 + c];
    float4 v = *(const float4*)(x + ((size_t)(b * CC + c0 + c)) * NT + n0 + tn);
    ts[c][tn]     = a * v.x + bb;
    ts[c][tn + 1] = a * v.y + bb;
    ts[c][tn + 2] = a * v.z + bb;
    ts[c][tn + 3] = a * v.w + bb;
  }
  __syncthreads();
#pragma unroll
  for (int it = 0; it < 2; it++) {
    int idx = tid + it * 256;
    int n = idx >> 3, c8 = (idx & 7) * 8;
    uint w[4];
#pragma unroll
    for (int j = 0; j < 4; j++) {
      ushort lo = f2bf(ts[c8 + 2 * j][n]);
      ushort hi = f2bf(ts[c8 + 2 * j + 1][n]);
      w[j] = (uint)lo | ((uint)hi << 16);
    }
    *(uint4*)&hT[((size_t)b * NT + n0 + n) * CC + c0 + c8] = make_uint4(w[0], w[1], w[2], w[3]);
  }
}

// ---------------- 128x128 MFMA mainloop (A*B^T, K-contig operands) ----------
template <int KTOT, int LDA, int LDB>
__device__ __forceinline__ void mfma_loop(const ushort* __restrict__ A,
                                          const ushort* __restrict__ B,
                                          ushort* As, ushort* Bs, int tid,
                                          f32x4 acc[4][4]) {
  int wave = tid >> 6, lane = tid & 63;
  int kofs = (lane & 3) * 8;
  int r0 = wave * 16 + (lane >> 2);
  int r1 = (wave + 4) * 16 + (lane >> 2);
  const ushort* ga0 = A + (size_t)r0 * LDA + kofs;
  const ushort* ga1 = A + (size_t)r1 * LDA + kofs;
  const ushort* gb0 = B + (size_t)r0 * LDB + kofs;
  const ushort* gb1 = B + (size_t)r1 * LDB + kofs;
  ushort* la0 = As + wave * 512;
  ushort* la1 = As + (wave + 4) * 512;
  ushort* lb0 = Bs + wave * 512;
  ushort* lb1 = Bs + (wave + 4) * 512;
  int wm = (wave >> 1) * 64, wn = (wave & 1) * 64;
  int aoff = (wm + (lane & 15)) * 32 + (lane >> 4) * 8;
  int boff = (wn + (lane & 15)) * 32 + (lane >> 4) * 8;
#pragma unroll 1
  for (int k0 = 0; k0 < KTOT; k0 += 32) {
    gload16(ga0, la0); gload16(ga1, la1);
    gload16(gb0, lb0); gload16(gb1, lb1);
    ga0 += 32; ga1 += 32; gb0 += 32; gb1 += 32;
    __syncthreads();
    bf16x8 a[4], b[4];
#pragma unroll
    for (int m = 0; m < 4; m++) a[m] = *(const bf16x8*)(As + aoff + m * 512);
#pragma unroll
    for (int n = 0; n < 4; n++) b[n] = *(const bf16x8*)(Bs + boff + n * 512);
#pragma unroll
    for (int m = 0; m < 4; m++)
#pragma unroll
      for (int n = 0; n < 4; n++)
        acc[m][n] = __builtin_amdgcn_mfma_f32_16x16x32_bf16(a[m], b[n], acc[m][n], 0, 0, 0);
    __syncthreads();
  }
}

// ---------------- 64x64 MFMA mainloop (A*B^T, K-contig operands) ------------
template <int KTOT, int LDA, int LDB>
__device__ __forceinline__ void mfma_loop64(const ushort* __restrict__ A,
                                            const ushort* __restrict__ B,
                                            ushort* As, ushort* Bs, int tid,
                                            f32x4 acc[2][2]) {
  int wave = tid >> 6, lane = tid & 63;
  int row = tid >> 2, kofs = (tid & 3) * 8;
  const ushort* ga = A + (size_t)row * LDA + kofs;
  const ushort* gb = B + (size_t)row * LDB + kofs;
  ushort* la = As + wave * 512;
  ushort* lb = Bs + wave * 512;
  int wm = (wave >> 1) * 32, wn = (wave & 1) * 32;
  int aoff = (wm + (lane & 15)) * 32 + (lane >> 4) * 8;
  int boff = (wn + (lane & 15)) * 32 + (lane >> 4) * 8;
#pragma unroll 1
  for (int k0 = 0; k0 < KTOT; k0 += 32) {
    gload16(ga, la); gload16(gb, lb);
    ga += 32; gb += 32;
    __syncthreads();
    bf16x8 a[2], b[2];
#pragma unroll
    for (int m = 0; m < 2; m++) a[m] = *(const bf16x8*)(As + aoff + m * 512);
#pragma unroll
    for (int n = 0; n < 2; n++) b[n] = *(const bf16x8*)(Bs + boff + n * 512);
#pragma unroll
    for (int m = 0; m < 2; m++)
#pragma unroll
      for (int n = 0; n < 2; n++)
        acc[m][n] = __builtin_amdgcn_mfma_f32_16x16x32_bf16(a[m], b[n], acc[m][n], 0, 0, 0);
    __syncthreads();
  }
}

// ---------------- kv GEMM bf16 ----------------
__global__ __launch_bounds__(256) void kv_gemm_bf16(
    const ushort* __restrict__ wkvb, const ushort* __restrict__ hT,
    const float* __restrict__ qkv_b, ushort* __restrict__ kvb) {
  __shared__ ushort As[4096], Bs[4096];
  int b = blockIdx.z, n0 = blockIdx.x * 128, m0 = blockIdx.y * 128;
  int tid = threadIdx.x;
  f32x4 acc[4][4] = {{{0.f, 0.f, 0.f, 0.f}}};
  mfma_loop<CC, CC, CC>(wkvb + (size_t)m0 * CC,
                        hT + (size_t)b * NT * CC + (size_t)n0 * CC, As, Bs, tid, acc);
  int wave = tid >> 6, lane = tid & 63;
  int wm = (wave >> 1) * 64, wn = (wave & 1) * 64;
  int col = lane & 15, rb = (lane >> 4) * 4;
#pragma unroll
  for (int m = 0; m < 4; m++)
#pragma unroll
    for (int n = 0; n < 4; n++)
#pragma unroll
      for (int j = 0; j < 4; j++) {
        int gm = m0 + wm + m * 16 + rb + j;
        int gn = n0 + wn + n * 16 + col;
        kvb[((size_t)(b * 1024 + gm)) * NT + gn] = f2bf(acc[m][n][j] + qkv_b[CC + gm]);
      }
}

// ---------------- softmax over tokens (bf16, k rows) ----------
__global__ __launch_bounds__(256) void softmax_bf16(ushort* __restrict__ kvb) {
  int row = blockIdx.x;
  int b = row >> 9, d = row & 511;
  ushort* p = kvb + ((size_t)(b * 1024 + d)) * NT;
  int tid = threadIdx.x;
  uint4 r0 = *(const uint4*)(p + tid * 16);
  uint4 r1 = *(const uint4*)(p + tid * 16 + 8);
  float v[16];
  uint ws_[8] = {r0.x, r0.y, r0.z, r0.w, r1.x, r1.y, r1.z, r1.w};
#pragma unroll
  for (int i = 0; i < 8; i++) {
    union { uint u; float f; } lo, hi;
    lo.u = ws_[i] << 16; hi.u = ws_[i] & 0xffff0000u;
    v[2 * i] = lo.f; v[2 * i + 1] = hi.f;
  }
  float mx = -1e30f;
#pragma unroll
  for (int i = 0; i < 16; i++) mx = fmaxf(mx, v[i]);
  for (int off = 32; off > 0; off >>= 1) mx = fmaxf(mx, __shfl_down(mx, off));
  __shared__ float red[4];
  __shared__ float bmx, bs;
  int wid = tid >> 6, lane = tid & 63;
  if (lane == 0) red[wid] = mx;
  __syncthreads();
  if (tid == 0) bmx = fmaxf(fmaxf(red[0], red[1]), fmaxf(red[2], red[3]));
  __syncthreads();
  mx = bmx;
  float s = 0.f;
#pragma unroll
  for (int i = 0; i < 16; i++) { v[i] = expf(v[i] - mx); s += v[i]; }
  for (int off = 32; off > 0; off >>= 1) s += __shfl_down(s, off);
  __syncthreads();
  if (lane == 0) red[wid] = s;
  __syncthreads();
  if (tid == 0) bs = red[0] + red[1] + red[2] + red[3];
  __syncthreads();
  float inv = 1.f / bs;
  uint out[8];
#pragma unroll
  for (int i = 0; i < 8; i++) {
    ushort lo = f2bf(v[2 * i] * inv);
    ushort hi = f2bf(v[2 * i + 1] * inv);
    out[i] = (uint)lo | ((uint)hi << 16);
  }
  *(uint4*)(p + tid * 16)     = make_uint4(out[0], out[1], out[2], out[3]);
  *(uint4*)(p + tid * 16 + 8) = make_uint4(out[4], out[5], out[6], out[7]);
}

// ---------------- ctx split-K: pctx[b,s,d,e] = sum_{n in split s} k v -------
__global__ __launch_bounds__(256) void ctx_gemm_split(
    const ushort* __restrict__ kvb, ushort* __restrict__ pctx) {
  __shared__ ushort As[4096], Bs[4096];
  int e0 = blockIdx.x * 128, d0 = blockIdx.y * 128;
  int bz = blockIdx.z, b = bz >> 3, s = bz & 7;
  int tid = threadIdx.x;
  f32x4 acc[4][4] = {{{0.f, 0.f, 0.f, 0.f}}};
  const ushort* K = kvb + (size_t)b * 1024 * NT + (size_t)d0 * NT + s * 512;
  const ushort* V = kvb + ((size_t)b * 1024 + 512) * NT + (size_t)e0 * NT + s * 512;
  mfma_loop<512, NT, NT>(K, V, As, Bs, tid, acc);
  int wave = tid >> 6, lane = tid & 63;
  int wm = (wave >> 1) * 64, wn = (wave & 1) * 64;
  int col = lane & 15, rb = (lane >> 4) * 4;
#pragma unroll
  for (int m = 0; m < 4; m++)
#pragma unroll
    for (int n = 0; n < 4; n++)
#pragma unroll
      for (int j = 0; j < 4; j++) {
        int gd = d0 + wm + m * 16 + rb + j;
        int ge = e0 + wn + n * 16 + col;
        pctx[((size_t)(b * 8 + s) * CC + gd) * CC + ge] = f2bf(acc[m][n][j]);
      }
}

// ---------------- reduce splits -> bf16 ctx ----------------
__global__ __launch_bounds__(256) void ctx_red(const ushort* __restrict__ pctx,
                                               ushort* __restrict__ ctxb) {
  int t = blockIdx.x * 256 + threadIdx.x;
  int b = t >> 15;
  int r = (t & 32767) * 8;
  const ushort* base = pctx + (size_t)b * 8 * 262144 + r;
  float f[8] = {};
#pragma unroll
  for (int s = 0; s < 8; s++) {
    uint4 v = *(const uint4*)(base + (size_t)s * 262144);
    uint w[4] = {v.x, v.y, v.z, v.w};
#pragma unroll
    for (int j = 0; j < 4; j++) {
      union { uint u; float f; } lo, hi;
      lo.u = w[j] << 16; hi.u = w[j] & 0xffff0000u;
      f[2 * j] += lo.f; f[2 * j + 1] += hi.f;
    }
  }
  uint o[4];
#pragma unroll
  for (int j = 0; j < 4; j++)
    o[j] = (uint)f2bf(f[2 * j]) | ((uint)f2bf(f[2 * j + 1]) << 16);
  *(uint4*)(ctxb + (size_t)b * 262144 + r) = make_uint4(o[0], o[1], o[2], o[3]);
}

// ---------------- M GEMM bf16: Mb[b,o,d] = SQK * sum_e pw[o,e] ctx[b,d,e] ---
__global__ __launch_bounds__(256) void m_gemm_bf16(
    const ushort* __restrict__ pwb, const ushort* __restrict__ ctxb,
    ushort* __restrict__ Mb) {
  __shared__ ushort As[2048], Bs[2048];
  int b = blockIdx.z, d0 = blockIdx.x * 64, o0 = blockIdx.y * 64;
  int tid = threadIdx.x;
  f32x4 acc[2][2] = {{{0.f, 0.f, 0.f, 0.f}}};
  mfma_loop64<CC, CC, CC>(pwb + (size_t)o0 * CC,
                          ctxb + (size_t)b * CC * CC + (size_t)d0 * CC, As, Bs, tid, acc);
  int wave = tid >> 6, lane = tid & 63;
  int wm = (wave >> 1) * 32, wn = (wave & 1) * 32;
  int col = lane & 15, rb = (lane >> 4) * 4;
#pragma unroll
  for (int m = 0; m < 2; m++)
#pragma unroll
    for (int n = 0; n < 2; n++)
#pragma unroll
      for (int j = 0; j < 4; j++) {
        int go = o0 + wm + m * 16 + rb + j;
        int gd = d0 + wn + n * 16 + col;
        Mb[((size_t)b * CC + go) * CC + gd] = f2bf(acc[m][n][j] * SQK);
      }
}

// ---------------- P GEMM bf16: Pb[b,o,c] = sum_d Mb[b,o,d] wqT[c,d] ---------
__global__ __launch_bounds__(256) void p_gemm_bf16(
    const ushort* __restrict__ Mb, const ushort* __restrict__ wqT,
    ushort* __restrict__ Pb) {
  __shared__ ushort As[2048], Bs[2048];
  int b = blockIdx.z, c0 = blockIdx.x * 64, o0 = blockIdx.y * 64;
  int tid = threadIdx.x;
  f32x4 acc[2][2] = {{{0.f, 0.f, 0.f, 0.f}}};
  mfma_loop64<CC, CC, CC>(Mb + (size_t)b * CC * CC + (size_t)o0 * CC,
                          wqT + (size_t)c0 * CC, As, Bs, tid, acc);
  int wave = tid >> 6, lane = tid & 63;
  int wm = (wave >> 1) * 32, wn = (wave & 1) * 32;
  int col = lane & 15, rb = (lane >> 4) * 4;
#pragma unroll
  for (int m = 0; m < 2; m++)
#pragma unroll
    for (int n = 0; n < 2; n++)
#pragma unroll
      for (int j = 0; j < 4; j++) {
        int go = o0 + wm + m * 16 + rb + j;
        int gc = c0 + wn + n * 16 + col;
        Pb[((size_t)b * CC + go) * CC + gc] = f2bf(acc[m][n][j]);
      }
}

// ---------------- pb2[b,o] = sum_d Mb[b,o,d]*qkv_b[d] + proj_b[o] ----------
__global__ __launch_bounds__(512) void pb2_kernel(
    const ushort* __restrict__ Mb, const float* __restrict__ qkv_b,
    const float* __restrict__ proj_b, float* __restrict__ pb2) {
  int b = blockIdx.x, o = threadIdx.x;
  const ushort* Mr = Mb + ((size_t)b * CC + o) * CC;
  float s = 0.f;
  for (int d = 0; d < CC; d++) s += bf2f(Mr[d]) * qkv_b[d];
  pb2[b * CC + o] = s + proj_b[o];
}

// ---------------- final GEMM bf16: out = x + P@h + pb2 ----------------------
__global__ __launch_bounds__(256) void final_gemm_bf16(
    const float* __restrict__ x, const ushort* __restrict__ Pb,
    const ushort* __restrict__ hT, const float* __restrict__ pb2,
    float* __restrict__ out) {
  __shared__ ushort As[4096], Bs[4096];
  int b = blockIdx.z, n0 = blockIdx.x * 128, m0 = blockIdx.y * 128;
  int tid = threadIdx.x;
  f32x4 acc[4][4] = {{{0.f, 0.f, 0.f, 0.f}}};
  mfma_loop<CC, CC, CC>(Pb + (size_t)b * CC * CC + (size_t)m0 * CC,
                        hT + (size_t)b * NT * CC + (size_t)n0 * CC, As, Bs, tid, acc);
  int wave = tid >> 6, lane = tid & 63;
  int wm = (wave >> 1) * 64, wn = (wave & 1) * 64;
  int col = lane & 15, rb = (lane >> 4) * 4;
#pragma unroll
  for (int m = 0; m < 4; m++)
#pragma unroll
    for (int n = 0; n < 4; n++)
#pragma unroll
      for (int j = 0; j < 4; j++) {
        int gm = m0 + wm + m * 16 + rb + j;
        int gn = n0 + wn + n * 16 + col;
        size_t idx = ((size_t)(b * CC + gm)) * NT + gn;
        out[idx] = acc[m][n][j] + pb2[b * CC + gm] + x[idx];
      }
}

extern "C" void kernel_launch(void* const* d_in, const int* in_sizes, int n_in,
                              void* d_out, int out_size, void* d_ws, size_t ws_size,
                              hipStream_t stream) {
  const float* x        = (const float*)d_in[0];
  const float* qkv_w    = (const float*)d_in[1];
  const float* qkv_b    = (const float*)d_in[2];
  const float* proj_w   = (const float*)d_in[3];
  const float* proj_b   = (const float*)d_in[4];
  const float* gn_scale = (const float*)d_in[5];
  const float* gn_bias  = (const float*)d_in[6];
  float* out = (float*)d_out;
  float* ws  = (float*)d_ws;

  float*  a_aff = ws + OFF_AAFF;
  float*  b_aff = ws + OFF_BAFF;
  float*  pb2   = ws + OFF_PB2;
  float*  red   = ws + OFF_RED;
  ushort* pctx  = (ushort*)(ws + OFF_PCTX);
  ushort* ctxb  = (ushort*)(ws + OFF_CTXB);
  ushort* wkvb  = (ushort*)(ws + OFF_WKV);
  ushort* pwb   = (ushort*)(ws + OFF_PW);
  ushort* wqT   = (ushort*)(ws + OFF_WQT);
  ushort* Mb    = (ushort*)(ws + OFF_MB);
  ushort* Pb    = (ushort*)(ws + OFF_PBF);
  ushort* hT    = (ushort*)(ws + OFF_HT);
  ushort* kvb   = (ushort*)(ws + OFF_KVB);

  gn_stats1<<<dim3(8, 64), 256, 0, stream>>>(x, red);
  gn_stats2<<<64, 64, 0, stream>>>(red, gn_scale, gn_bias, a_aff, b_aff);
  wconv_kv<<<512, 256, 0, stream>>>(qkv_w, wkvb);
  wconv_pw<<<256, 256, 0, stream>>>(proj_w, pwb);
  wqt_kernel<<<dim3(16, 16), 256, 0, stream>>>(qkv_w, wqT);
  ht_kernel<<<dim3(64, 8, 8), 256, 0, stream>>>(x, a_aff, b_aff, hT);
  kv_gemm_bf16<<<dim3(32, 8, 8), 256, 0, stream>>>(wkvb, hT, qkv_b, kvb);
  softmax_bf16<<<4096, 256, 0, stream>>>(kvb);
  ctx_gemm_split<<<dim3(4, 4, 64), 256, 0, stream>>>(kvb, pctx);
  ctx_red<<<1024, 256, 0, stream>>>(pctx, ctxb);
  m_gemm_bf16<<<dim3(8, 8, 8), 256, 0, stream>>>(pwb, ctxb, Mb);
  p_gemm_bf16<<<dim3(8, 8, 8), 256, 0, stream>>>(Mb, wqT, Pb);
  pb2_kernel<<<8, 512, 0, stream>>>(Mb, qkv_b, proj_b, pb2);
  final_gemm_bf16<<<dim3(32, 4, 8), 256, 0, stream>>>(x, Pb, hT, pb2, out);
}